// Round 16
// baseline (227.092 us; speedup 1.0000x reference)
//
#include <hip/hip_runtime.h>
#include <math.h>

#define D2 50
#define D3 15
#define D5 10
#define NC 6
#define SCAN_B 512
#define GS 32     // gsum row stride: [0..14]=sum x2, [16..30]=sum relu(x2)
#define SPLIT 4   // tail blocks per graph

typedef _Float16 h2 __attribute__((ext_vector_type(2)));
typedef __fp16   fp16x2 __attribute__((ext_vector_type(2)));

__device__ __forceinline__ float fdot2(h2 a, h2 b, float c) {
#if __has_builtin(__builtin_amdgcn_fdot2)
    return __builtin_amdgcn_fdot2(a, b, c, false);
#else
    return c + (float)a[0] * (float)b[0] + (float)a[1] * (float)b[1];
#endif
}

__device__ __forceinline__ h2 pkrtz(float a, float b) {
#if __has_builtin(__builtin_amdgcn_cvt_pkrtz)
    fp16x2 r = __builtin_amdgcn_cvt_pkrtz(a, b);
    return __builtin_bit_cast(h2, r);
#else
    h2 v; v[0] = (_Float16)a; v[1] = (_Float16)b; return v;
#endif
}

// ---------------------------------------------------------------------------
// Kernel A: degree + rank (one int atomic per edge). Block 0 also packs the
// MLP weights into f16 pairs. (round-13 proven)
// ---------------------------------------------------------------------------
__global__ __launch_bounds__(256) void deg_rank_prep_kernel(
    const int* __restrict__ ei, int* __restrict__ deg, int* __restrict__ rank, int E,
    const float* __restrict__ ew1, const float* __restrict__ nw1,
    const float* __restrict__ ew2, const float* __restrict__ nw2,
    h2* __restrict__ ew1pk, h2* __restrict__ nw1pk,
    h2* __restrict__ ew2pk, h2* __restrict__ nw2pk)
{
    int e = blockIdx.x * blockDim.x + threadIdx.x;
    if (e < E) {
        int r = ei[e];
        rank[e] = atomicAdd(&deg[r], 1);
    }
    if (blockIdx.x == 0) {
        int t = threadIdx.x;
        for (int i = t; i < D2 * 5; i += 256) {
            int j = i / 5, p = i - 5 * j;
            float a = ew1[(2 * p) * D2 + j];
            float b = (2 * p + 1 < 9) ? ew1[(2 * p + 1) * D2 + j] : 0.0f;
            h2 v; v[0] = (_Float16)a; v[1] = (_Float16)b;
            ew1pk[i] = v;
        }
        for (int i = t; i < D2 * 9; i += 256) {
            int j = i / 9, p = i - 9 * j;
            float a = nw1[(2 * p) * D2 + j];
            float b = nw1[(2 * p + 1) * D2 + j];
            h2 v; v[0] = (_Float16)a; v[1] = (_Float16)b;
            nw1pk[i] = v;
        }
        for (int i = t; i < D3 * 25; i += 256) {
            int m = i / 25, k = i - 25 * m;
            float a = ew2[(2 * k) * D3 + m];
            float b = ew2[(2 * k + 1) * D3 + m];
            h2 v; v[0] = (_Float16)a; v[1] = (_Float16)b;
            ew2pk[i] = v;
            float c = nw2[(2 * k) * D3 + m];
            float d = nw2[(2 * k + 1) * D3 + m];
            h2 w; w[0] = (_Float16)c; w[1] = (_Float16)d;
            nw2pk[i] = w;
        }
    }
}

// ---------------------------------------------------------------------------
// Scan phase 1: per-block inclusive scan of deg -> exclusive base + block sums.
// ---------------------------------------------------------------------------
__global__ __launch_bounds__(SCAN_B) void scan1_kernel(
    const int* __restrict__ deg, int* __restrict__ base, int* __restrict__ bsum, int N)
{
    __shared__ int sm[SCAN_B];
    int i = blockIdx.x * SCAN_B + threadIdx.x;
    int v = (i < N) ? deg[i] : 0;
    sm[threadIdx.x] = v;
    __syncthreads();
    #pragma unroll
    for (int s = 1; s < SCAN_B; s <<= 1) {
        int t = (threadIdx.x >= (unsigned)s) ? sm[threadIdx.x - s] : 0;
        __syncthreads();
        sm[threadIdx.x] += t;
        __syncthreads();
    }
    if (i < N) base[i] = sm[threadIdx.x] - v;   // exclusive
    if (threadIdx.x == SCAN_B - 1) bsum[blockIdx.x] = sm[threadIdx.x];
}

// ---------------------------------------------------------------------------
// Scan phase 2+3 fused: each block sums bsum[0..bid) itself, adds to base.
// ---------------------------------------------------------------------------
__global__ __launch_bounds__(SCAN_B) void scan23_kernel(
    int* __restrict__ base, const int* __restrict__ bsum, int N)
{
    int bid = blockIdx.x;
    int sum = 0;
    for (int t = (int)threadIdx.x; t < bid; t += SCAN_B) sum += bsum[t];
    #pragma unroll
    for (int s = 32; s > 0; s >>= 1) sum += __shfl_down(sum, s);
    __shared__ int ws[SCAN_B / 64];
    __shared__ int s_total;
    int lane = threadIdx.x & 63, wid = threadIdx.x >> 6;
    if (lane == 0) ws[wid] = sum;
    __syncthreads();
    if (threadIdx.x == 0) {
        int tot = 0;
        #pragma unroll
        for (int w = 0; w < SCAN_B / 64; ++w) tot += ws[w];
        s_total = tot;
    }
    __syncthreads();
    int i = bid * SCAN_B + threadIdx.x;
    if (i < N) base[i] += s_total;
}

// ---------------------------------------------------------------------------
// Kernel C: fused edge+node MLP via v_dot2_f32_f16 (round-13 proven, 105us).
// ---------------------------------------------------------------------------
__global__ __launch_bounds__(256, 4) void edge_mlp_fused_kernel(
    const float* __restrict__ x,
    const int*   __restrict__ ei,
    const float* __restrict__ ea,
    const h2* __restrict__ ew1pk, const float* __restrict__ eb1,
    const h2* __restrict__ ew2pk, const float* __restrict__ eb2,
    const h2* __restrict__ nw1pk, const float* __restrict__ nb1,
    const h2* __restrict__ nw2pk, const float* __restrict__ nb2,
    const int* __restrict__ base, const int* __restrict__ rank,
    unsigned int* __restrict__ hbuf16,
    int E)
{
    int e = blockIdx.x * blockDim.x + threadIdx.x;
    if (e >= E) return;

    int r = ei[e];
    int c = ei[E + e];
    int slot = base[r] + rank[e];

    float in9[9];
    in9[0] = x[3 * r + 0];
    in9[1] = x[3 * r + 1];
    in9[2] = x[3 * r + 2];
    in9[3] = x[3 * c + 0];
    in9[4] = x[3 * c + 1];
    in9[5] = x[3 * c + 2];
    in9[6] = ea[3 * (size_t)e + 0];
    in9[7] = ea[3 * (size_t)e + 1];
    in9[8] = ea[3 * (size_t)e + 2];

    h2 inpk[5];
    inpk[0] = pkrtz(in9[0], in9[1]);
    inpk[1] = pkrtz(in9[2], in9[3]);
    inpk[2] = pkrtz(in9[4], in9[5]);
    inpk[3] = pkrtz(in9[6], in9[7]);
    inpk[4] = pkrtz(in9[8], 0.0f);

    // edge MLP layer 1: 9 -> 50 (relu), kept packed
    h2 hpk[25];
    #pragma unroll
    for (int jj = 0; jj < 25; ++jj) {
        float a0 = eb1[2 * jj];
        float a1 = eb1[2 * jj + 1];
        #pragma unroll
        for (int p = 0; p < 5; ++p) {
            a0 = fdot2(inpk[p], ew1pk[(2 * jj) * 5 + p], a0);
            a1 = fdot2(inpk[p], ew1pk[(2 * jj + 1) * 5 + p], a1);
        }
        hpk[jj] = pkrtz(fmaxf(a0, 0.0f), fmaxf(a1, 0.0f));
    }

    // edge MLP layer 2: 50 -> 15
    float e2v[D3];
    #pragma unroll
    for (int m = 0; m < D3; ++m) {
        float a = eb2[m];
        #pragma unroll
        for (int k = 0; k < 25; ++k) a = fdot2(hpk[k], ew2pk[m * 25 + k], a);
        e2v[m] = a;
    }

    // node-MLP input: [xc(3), e2(15)] = 18 -> 9 pairs
    h2 vpk[9];
    vpk[0] = pkrtz(in9[3], in9[4]);
    vpk[1] = pkrtz(in9[5], e2v[0]);
    #pragma unroll
    for (int p = 2; p < 9; ++p) vpk[p] = pkrtz(e2v[2 * p - 3], e2v[2 * p - 2]);

    // node MLP layer 1: 18 -> 50 (relu), kept packed
    h2 h2pk[25];
    #pragma unroll
    for (int jj = 0; jj < 25; ++jj) {
        float a0 = nb1[2 * jj];
        float a1 = nb1[2 * jj + 1];
        #pragma unroll
        for (int p = 0; p < 9; ++p) {
            a0 = fdot2(vpk[p], nw1pk[(2 * jj) * 9 + p], a0);
            a1 = fdot2(vpk[p], nw1pk[(2 * jj + 1) * 9 + p], a1);
        }
        h2pk[jj] = pkrtz(fmaxf(a0, 0.0f), fmaxf(a1, 0.0f));
    }

    // node MLP layer 2: 50 -> 15, pack to f16, 32B store
    float acc[D3 + 1];
    #pragma unroll
    for (int m = 0; m < D3; ++m) {
        float a = nb2[m];
        #pragma unroll
        for (int k = 0; k < 25; ++k) a = fdot2(h2pk[k], nw2pk[m * 25 + k], a);
        acc[m] = a;
    }
    acc[D3] = 0.0f;

    union { h2 h[8]; uint4 u[2]; } outp;
    #pragma unroll
    for (int p = 0; p < 8; ++p) outp.h[p] = pkrtz(acc[2 * p], acc[2 * p + 1]);

    uint4* dst = (uint4*)(hbuf16 + (size_t)slot * 8);
    dst[0] = outp.u[0];
    dst[1] = outp.u[1];
}

// ---------------------------------------------------------------------------
// Kernel T1 (NEW): tail partial reduction. SPLIT blocks per graph, each takes
// a contiguous chunk of the graph's nodes, runs the round-9-proven per-node
// loop, block-reduces, and flushes ONE set of 30 atomicAdds into gsum.
// ---------------------------------------------------------------------------
__global__ __launch_bounds__(256) void tail_partial_kernel(
    const unsigned int* __restrict__ hbuf16,
    const int* __restrict__ deg, const int* __restrict__ base,
    const int* __restrict__ batch, int N,
    float* __restrict__ gsum)
{
    int b = blockIdx.x / SPLIT;
    int q = blockIdx.x % SPLIT;
    int tid = threadIdx.x;

    int lo = 0, hi = N;
    while (lo < hi) { int m = (lo + hi) >> 1; if (batch[m] < b) lo = m + 1; else hi = m; }
    int start = lo;
    hi = N;
    while (lo < hi) { int m = (lo + hi) >> 1; if (batch[m] < b + 1) lo = m + 1; else hi = m; }
    int end = lo;

    int len = end - start;
    int cs = start + (int)(((long long)len * q) / SPLIT);
    int ce = start + (int)(((long long)len * (q + 1)) / SPLIT);

    float sx[D3], sr[D3];
    #pragma unroll
    for (int j = 0; j < D3; ++j) { sx[j] = 0.0f; sr[j] = 0.0f; }

    for (int i = cs + tid; i < ce; i += 256) {
        int bs = base[i];
        int d  = deg[i];
        float acc[16];
        #pragma unroll
        for (int j = 0; j < 16; ++j) acc[j] = 0.0f;
        const uint4* ptr = (const uint4*)(hbuf16 + (size_t)bs * 8);
        for (int k = 0; k < d; ++k) {
            uint4 w0 = ptr[2 * k];
            uint4 w1 = ptr[2 * k + 1];
            unsigned int ws[8] = {w0.x, w0.y, w0.z, w0.w, w1.x, w1.y, w1.z, w1.w};
            #pragma unroll
            for (int p = 0; p < 8; ++p) {
                h2 v = __builtin_bit_cast(h2, ws[p]);
                acc[2 * p]     += (float)v[0];
                acc[2 * p + 1] += (float)v[1];
            }
        }
        float inv = 1.0f / fmaxf((float)d, 1.0f);
        #pragma unroll
        for (int j = 0; j < D3; ++j) {
            float v = acc[j] * inv;
            sx[j] += v;
            sr[j] += fmaxf(v, 0.0f);
        }
    }

    #pragma unroll
    for (int j = 0; j < D3; ++j) {
        #pragma unroll
        for (int s = 32; s > 0; s >>= 1) {
            sx[j] += __shfl_down(sx[j], s);
            sr[j] += __shfl_down(sr[j], s);
        }
    }

    __shared__ float sm[4][2 * D3];
    int lane = tid & 63, wid = tid >> 6;
    if (lane == 0) {
        #pragma unroll
        for (int j = 0; j < D3; ++j) { sm[wid][j] = sx[j]; sm[wid][D3 + j] = sr[j]; }
    }
    __syncthreads();

    if (tid < 2 * D3) {
        float v = sm[0][tid] + sm[1][tid] + sm[2][tid] + sm[3][tid];
        int off = (tid < D3) ? tid : (16 + tid - D3);
        atomicAdd(&gsum[(size_t)b * GS + off], v);
    }
}

// ---------------------------------------------------------------------------
// Kernel T2: per-graph head. Thread = graph. Count via binary search.
// ---------------------------------------------------------------------------
__global__ __launch_bounds__(256) void final_head_kernel(
    const float* __restrict__ gsum, const int* __restrict__ batch, int N,
    const float* __restrict__ u,
    const float* __restrict__ gw1, const float* __restrict__ gb1,
    const float* __restrict__ gw2, const float* __restrict__ gb2,
    const float* __restrict__ fc1w, const float* __restrict__ fc1b,
    const float* __restrict__ bng, const float* __restrict__ bnb,
    const float* __restrict__ fc2w, const float* __restrict__ fc2b,
    float* __restrict__ out, int B)
{
    int t = blockIdx.x * blockDim.x + threadIdx.x;
    if (t >= B) return;

    int lo = 0, hi = N;
    while (lo < hi) { int m = (lo + hi) >> 1; if (batch[m] < t) lo = m + 1; else hi = m; }
    int start = lo;
    hi = N;
    while (lo < hi) { int m = (lo + hi) >> 1; if (batch[m] < t + 1) lo = m + 1; else hi = m; }
    float nct = (float)(lo - start);

    float in16[16];
    in16[0] = u[t];
    float invn = 1.0f / fmaxf(nct, 1.0f);
    #pragma unroll
    for (int j = 0; j < D3; ++j) in16[1 + j] = gsum[(size_t)t * GS + j] * invn;

    float gh[D2];
    #pragma unroll
    for (int j = 0; j < D2; ++j) {
        float a = gb1[j];
        #pragma unroll
        for (int k = 0; k < 16; ++k) a = fmaf(in16[k], gw1[k * D2 + j], a);
        gh[j] = fmaxf(a, 0.0f);
    }

    float g[D3];
    #pragma unroll
    for (int j = 0; j < D3; ++j) {
        float a = gb2[j];
        #pragma unroll
        for (int k = 0; k < D2; ++k) a = fmaf(gh[k], gw2[k * D3 + j], a);
        g[j] = (gsum[(size_t)t * GS + 16 + j] + fmaxf(a, 0.0f)) / (nct + 1.0f);
    }

    const float bnscale = 1.0f / sqrtf(1.0f + 1e-5f);
    float h1[D5];
    #pragma unroll
    for (int i = 0; i < D5; ++i) {
        float a = fc1b[i];
        #pragma unroll
        for (int k = 0; k < D3; ++k) a = fmaf(g[k], fc1w[k * D5 + i], a);
        h1[i] = fmaxf(a * (bng[i] * bnscale) + bnb[i], 0.0f);
    }

    float o[NC];
    #pragma unroll
    for (int j = 0; j < NC; ++j) {
        float a = fc2b[j];
        #pragma unroll
        for (int k = 0; k < D5; ++k) a = fmaf(h1[k], fc2w[k * NC + j], a);
        o[j] = a;
    }
    float m = o[0];
    #pragma unroll
    for (int j = 1; j < NC; ++j) m = fmaxf(m, o[j]);
    float ssum = 0.0f;
    #pragma unroll
    for (int j = 0; j < NC; ++j) ssum += expf(o[j] - m);
    float lse = m + logf(ssum);
    #pragma unroll
    for (int j = 0; j < NC; ++j) out[t * NC + j] = o[j] - lse;
}

// ---------------------------------------------------------------------------
// Fallback (round-1) kernels: atomic scatter-mean. Used only if ws too small.
// ---------------------------------------------------------------------------
__global__ __launch_bounds__(256) void edge_node_atomic_kernel(
    const float* __restrict__ x,
    const int*   __restrict__ ei,
    const float* __restrict__ ea,
    const float* __restrict__ ew1, const float* __restrict__ eb1,
    const float* __restrict__ ew2, const float* __restrict__ eb2,
    const float* __restrict__ nw1, const float* __restrict__ nb1,
    const float* __restrict__ nw2, const float* __restrict__ nb2,
    float* __restrict__ x2sum, float* __restrict__ cnt,
    int E)
{
    int e = blockIdx.x * blockDim.x + threadIdx.x;
    if (e >= E) return;
    int r = ei[e];
    int c = ei[E + e];
    float in9[9];
    in9[0] = x[3 * r + 0]; in9[1] = x[3 * r + 1]; in9[2] = x[3 * r + 2];
    float xc0 = x[3 * c + 0], xc1 = x[3 * c + 1], xc2 = x[3 * c + 2];
    in9[3] = xc0; in9[4] = xc1; in9[5] = xc2;
    in9[6] = ea[3 * e + 0]; in9[7] = ea[3 * e + 1]; in9[8] = ea[3 * e + 2];
    float h[D2];
    #pragma unroll
    for (int j = 0; j < D2; ++j) {
        float a = eb1[j];
        #pragma unroll
        for (int k = 0; k < 9; ++k) a = fmaf(in9[k], ew1[k * D2 + j], a);
        h[j] = fmaxf(a, 0.0f);
    }
    float e2[D3];
    #pragma unroll
    for (int j = 0; j < D3; ++j) {
        float a = eb2[j];
        #pragma unroll
        for (int k = 0; k < D2; ++k) a = fmaf(h[k], ew2[k * D3 + j], a);
        e2[j] = a;
    }
    float h2v[D2];
    #pragma unroll
    for (int j = 0; j < D2; ++j) {
        float a = nb1[j];
        a = fmaf(xc0, nw1[0 * D2 + j], a);
        a = fmaf(xc1, nw1[1 * D2 + j], a);
        a = fmaf(xc2, nw1[2 * D2 + j], a);
        #pragma unroll
        for (int k = 0; k < D3; ++k) a = fmaf(e2[k], nw1[(3 + k) * D2 + j], a);
        h2v[j] = fmaxf(a, 0.0f);
    }
    float* dst = x2sum + (size_t)r * D3;
    #pragma unroll
    for (int j = 0; j < D3; ++j) {
        float a = nb2[j];
        #pragma unroll
        for (int k = 0; k < D2; ++k) a = fmaf(h2v[k], nw2[k * D3 + j], a);
        atomicAdd(&dst[j], a);
    }
    atomicAdd(&cnt[r], 1.0f);
}

__global__ __launch_bounds__(256) void graph_sum_atomic_kernel(
    const float* __restrict__ x2sum, const float* __restrict__ cnt,
    const int* __restrict__ batch, int N,
    float* __restrict__ bx, float* __restrict__ brelu, float* __restrict__ ncnt)
{
    int b = blockIdx.x;
    int lo = 0, hi = N;
    while (lo < hi) { int m = (lo + hi) >> 1; if (batch[m] < b) lo = m + 1; else hi = m; }
    int start = lo;
    hi = N;
    while (lo < hi) { int m = (lo + hi) >> 1; if (batch[m] < b + 1) lo = m + 1; else hi = m; }
    int end = lo;
    float sx[D3], sr[D3];
    #pragma unroll
    for (int j = 0; j < D3; ++j) { sx[j] = 0.0f; sr[j] = 0.0f; }
    for (int i = start + (int)threadIdx.x; i < end; i += (int)blockDim.x) {
        float inv = 1.0f / fmaxf(cnt[i], 1.0f);
        #pragma unroll
        for (int j = 0; j < D3; ++j) {
            float v = x2sum[(size_t)i * D3 + j] * inv;
            sx[j] += v;
            sr[j] += fmaxf(v, 0.0f);
        }
    }
    #pragma unroll
    for (int j = 0; j < D3; ++j) {
        #pragma unroll
        for (int s = 32; s > 0; s >>= 1) {
            sx[j] += __shfl_down(sx[j], s);
            sr[j] += __shfl_down(sr[j], s);
        }
    }
    __shared__ float sm[4][2 * D3];
    int lane = threadIdx.x & 63, wid = threadIdx.x >> 6;
    if (lane == 0) {
        #pragma unroll
        for (int j = 0; j < D3; ++j) { sm[wid][j] = sx[j]; sm[wid][D3 + j] = sr[j]; }
    }
    __syncthreads();
    if (threadIdx.x < 2 * D3) {
        float v = sm[0][threadIdx.x] + sm[1][threadIdx.x] + sm[2][threadIdx.x] + sm[3][threadIdx.x];
        if (threadIdx.x < D3) bx[b * D3 + threadIdx.x] = v;
        else                  brelu[b * D3 + (threadIdx.x - D3)] = v;
    }
    if (threadIdx.x == 0) ncnt[b] = (float)(end - start);
}

__global__ __launch_bounds__(256) void final_kernel(
    const float* __restrict__ u,
    const float* __restrict__ gw1, const float* __restrict__ gb1,
    const float* __restrict__ gw2, const float* __restrict__ gb2,
    const float* __restrict__ fc1w, const float* __restrict__ fc1b,
    const float* __restrict__ bng, const float* __restrict__ bnb,
    const float* __restrict__ fc2w, const float* __restrict__ fc2b,
    const float* __restrict__ bx, const float* __restrict__ brelu,
    const float* __restrict__ ncnt,
    float* __restrict__ out, int B)
{
    int t = blockIdx.x * blockDim.x + threadIdx.x;
    if (t >= B) return;
    float nct = ncnt[t];
    float inv = 1.0f / fmaxf(nct, 1.0f);
    float in16[16];
    in16[0] = u[t];
    #pragma unroll
    for (int j = 0; j < D3; ++j) in16[1 + j] = bx[t * D3 + j] * inv;
    float gh[D2];
    #pragma unroll
    for (int j = 0; j < D2; ++j) {
        float a = gb1[j];
        #pragma unroll
        for (int k = 0; k < 16; ++k) a = fmaf(in16[k], gw1[k * D2 + j], a);
        gh[j] = fmaxf(a, 0.0f);
    }
    float g[D3];
    #pragma unroll
    for (int j = 0; j < D3; ++j) {
        float a = gb2[j];
        #pragma unroll
        for (int k = 0; k < D2; ++k) a = fmaf(gh[k], gw2[k * D3 + j], a);
        g[j] = (brelu[t * D3 + j] + fmaxf(a, 0.0f)) / (nct + 1.0f);
    }
    const float bnscale = 1.0f / sqrtf(1.0f + 1e-5f);
    float h1[D5];
    #pragma unroll
    for (int i = 0; i < D5; ++i) {
        float a = fc1b[i];
        #pragma unroll
        for (int k = 0; k < D3; ++k) a = fmaf(g[k], fc1w[k * D5 + i], a);
        h1[i] = fmaxf(a * (bng[i] * bnscale) + bnb[i], 0.0f);
    }
    float o[NC];
    #pragma unroll
    for (int j = 0; j < NC; ++j) {
        float a = fc2b[j];
        #pragma unroll
        for (int k = 0; k < D5; ++k) a = fmaf(h1[k], fc2w[k * NC + j], a);
        o[j] = a;
    }
    float m = o[0];
    #pragma unroll
    for (int j = 1; j < NC; ++j) m = fmaxf(m, o[j]);
    float ssum = 0.0f;
    #pragma unroll
    for (int j = 0; j < NC; ++j) ssum += expf(o[j] - m);
    float lse = m + logf(ssum);
    #pragma unroll
    for (int j = 0; j < NC; ++j) out[t * NC + j] = o[j] - lse;
}

extern "C" void kernel_launch(void* const* d_in, const int* in_sizes, int n_in,
                              void* d_out, int out_size, void* d_ws, size_t ws_size,
                              hipStream_t stream) {
    const float* x     = (const float*)d_in[0];
    const int*   ei    = (const int*)  d_in[1];
    const float* ea    = (const float*)d_in[2];
    const float* u     = (const float*)d_in[3];
    const int*   batch = (const int*)  d_in[4];
    const float* ew1 = (const float*)d_in[5];
    const float* eb1 = (const float*)d_in[6];
    const float* ew2 = (const float*)d_in[7];
    const float* eb2 = (const float*)d_in[8];
    const float* nw1 = (const float*)d_in[9];
    const float* nb1 = (const float*)d_in[10];
    const float* nw2 = (const float*)d_in[11];
    const float* nb2 = (const float*)d_in[12];
    const float* gw1 = (const float*)d_in[13];
    const float* gb1 = (const float*)d_in[14];
    const float* gw2 = (const float*)d_in[15];
    const float* gb2 = (const float*)d_in[16];
    const float* fc1w = (const float*)d_in[17];
    const float* fc1b = (const float*)d_in[18];
    const float* bng  = (const float*)d_in[19];
    const float* bnb  = (const float*)d_in[20];
    const float* fc2w = (const float*)d_in[21];
    const float* fc2b = (const float*)d_in[22];

    int N = in_sizes[0] / 3;
    int E = in_sizes[2] / 3;
    int B = in_sizes[3];
    float* out = (float*)d_out;

    int nsb = (N + SCAN_B - 1) / SCAN_B;   // scan blocks (196 for N=100K)
    const size_t WPK = 2048;               // packed weights (h2), padded

    size_t need = sizeof(h2) * WPK
                + sizeof(unsigned int) * (size_t)E * 8                 /* hbuf16 */
                + sizeof(int) * (size_t)N                              /* deg    */
                + sizeof(float) * (size_t)B * GS                       /* gsum   */
                + sizeof(int) * ((size_t)E + (size_t)N + 1024);        /* rank, base, bsum */

    if (ws_size >= need && nsb <= 1024) {
        // ---- fast path: CSR build + dot2 MLP + split tail ----
        char* p = (char*)d_ws;
        h2* ew1pk = (h2*)p;                 // 250
        h2* nw1pk = ew1pk + 250;            // 450
        h2* ew2pk = nw1pk + 450;            // 375
        h2* nw2pk = ew2pk + 375;            // 375
        p += sizeof(h2) * WPK;
        unsigned int* hbuf16 = (unsigned int*)p;  p += sizeof(unsigned int) * (size_t)E * 8;
        int* deg    = (int*)p;          p += sizeof(int) * (size_t)N;
        float* gsum = (float*)p;        p += sizeof(float) * (size_t)B * GS;
        int* rank = (int*)p;            p += sizeof(int) * (size_t)E;
        int* base = (int*)p;            p += sizeof(int) * (size_t)N;
        int* bsum = (int*)p;            p += sizeof(int) * 1024;

        // single memset covers deg (N ints) + gsum (B*GS floats), contiguous
        hipMemsetAsync(deg, 0, sizeof(int) * (size_t)N + sizeof(float) * (size_t)B * GS, stream);

        int eb = (E + 255) / 256;
        deg_rank_prep_kernel<<<eb, 256, 0, stream>>>(
            ei, deg, rank, E, ew1, nw1, ew2, nw2, ew1pk, nw1pk, ew2pk, nw2pk);

        scan1_kernel<<<nsb, SCAN_B, 0, stream>>>(deg, base, bsum, N);
        scan23_kernel<<<nsb, SCAN_B, 0, stream>>>(base, bsum, N);

        edge_mlp_fused_kernel<<<eb, 256, 0, stream>>>(
            x, ei, ea, ew1pk, eb1, ew2pk, eb2, nw1pk, nb1, nw2pk, nb2,
            base, rank, hbuf16, E);

        tail_partial_kernel<<<B * SPLIT, 256, 0, stream>>>(
            hbuf16, deg, base, batch, N, gsum);

        int fb = (B + 255) / 256;
        final_head_kernel<<<fb, 256, 0, stream>>>(
            gsum, batch, N, u, gw1, gb1, gw2, gb2,
            fc1w, fc1b, bng, bnb, fc2w, fc2b, out, B);
    } else {
        // ---- fallback: round-1 atomic path (fp32 exact) ----
        float* x2sum = (float*)d_ws;
        float* cnt   = x2sum + (size_t)N * D3;
        float* bx    = cnt + N;
        float* brelu = bx + (size_t)B * D3;
        float* ncnt  = brelu + (size_t)B * D3;

        hipMemsetAsync(x2sum, 0, sizeof(float) * ((size_t)N * D3 + N), stream);

        int eb = (E + 255) / 256;
        edge_node_atomic_kernel<<<eb, 256, 0, stream>>>(
            x, ei, ea, ew1, eb1, ew2, eb2, nw1, nb1, nw2, nb2, x2sum, cnt, E);

        graph_sum_atomic_kernel<<<B, 256, 0, stream>>>(x2sum, cnt, batch, N, bx, brelu, ncnt);

        int fb = (B + 255) / 256;
        final_kernel<<<fb, 256, 0, stream>>>(
            u, gw1, gb1, gw2, gb2, fc1w, fc1b, bng, bnb, fc2w, fc2b,
            bx, brelu, ncnt, out, B);
    }
}

// Round 17
// 207.053 us; speedup vs baseline: 1.0968x; 1.0968x over previous
//
#include <hip/hip_runtime.h>
#include <math.h>

#define D1 3
#define D2 50
#define D3 15
#define D5 10
#define NC 6
#define SCAN_B 512

typedef _Float16 h2 __attribute__((ext_vector_type(2)));
typedef __fp16   fp16x2 __attribute__((ext_vector_type(2)));

__device__ __forceinline__ float fdot2(h2 a, h2 b, float c) {
#if __has_builtin(__builtin_amdgcn_fdot2)
    return __builtin_amdgcn_fdot2(a, b, c, false);
#else
    return c + (float)a[0] * (float)b[0] + (float)a[1] * (float)b[1];
#endif
}

__device__ __forceinline__ h2 pkrtz(float a, float b) {
#if __has_builtin(__builtin_amdgcn_cvt_pkrtz)
    fp16x2 r = __builtin_amdgcn_cvt_pkrtz(a, b);
    return __builtin_bit_cast(h2, r);
#else
    h2 v; v[0] = (_Float16)a; v[1] = (_Float16)b; return v;
#endif
}

// ---------------------------------------------------------------------------
// Kernel A: degree + rank (one int atomic per edge). Block 0 also packs the
// MLP weights into f16 pairs.
// ---------------------------------------------------------------------------
__global__ __launch_bounds__(256) void deg_rank_prep_kernel(
    const int* __restrict__ ei, int* __restrict__ deg, int* __restrict__ rank, int E,
    const float* __restrict__ ew1, const float* __restrict__ nw1,
    const float* __restrict__ ew2, const float* __restrict__ nw2,
    h2* __restrict__ ew1pk, h2* __restrict__ nw1pk,
    h2* __restrict__ ew2pk, h2* __restrict__ nw2pk)
{
    int e = blockIdx.x * blockDim.x + threadIdx.x;
    if (e < E) {
        int r = ei[e];
        rank[e] = atomicAdd(&deg[r], 1);
    }
    if (blockIdx.x == 0) {
        int t = threadIdx.x;
        for (int i = t; i < D2 * 5; i += 256) {
            int j = i / 5, p = i - 5 * j;
            float a = ew1[(2 * p) * D2 + j];
            float b = (2 * p + 1 < 9) ? ew1[(2 * p + 1) * D2 + j] : 0.0f;
            h2 v; v[0] = (_Float16)a; v[1] = (_Float16)b;
            ew1pk[i] = v;
        }
        for (int i = t; i < D2 * 9; i += 256) {
            int j = i / 9, p = i - 9 * j;
            float a = nw1[(2 * p) * D2 + j];
            float b = nw1[(2 * p + 1) * D2 + j];
            h2 v; v[0] = (_Float16)a; v[1] = (_Float16)b;
            nw1pk[i] = v;
        }
        for (int i = t; i < D3 * 25; i += 256) {
            int m = i / 25, k = i - 25 * m;
            float a = ew2[(2 * k) * D3 + m];
            float b = ew2[(2 * k + 1) * D3 + m];
            h2 v; v[0] = (_Float16)a; v[1] = (_Float16)b;
            ew2pk[i] = v;
            float c = nw2[(2 * k) * D3 + m];
            float d = nw2[(2 * k + 1) * D3 + m];
            h2 w; w[0] = (_Float16)c; w[1] = (_Float16)d;
            nw2pk[i] = w;
        }
    }
}

// ---------------------------------------------------------------------------
// Scan phase 1: per-block inclusive scan of deg -> exclusive base + block sums.
// ---------------------------------------------------------------------------
__global__ __launch_bounds__(SCAN_B) void scan1_kernel(
    const int* __restrict__ deg, int* __restrict__ base, int* __restrict__ bsum, int N)
{
    __shared__ int sm[SCAN_B];
    int i = blockIdx.x * SCAN_B + threadIdx.x;
    int v = (i < N) ? deg[i] : 0;
    sm[threadIdx.x] = v;
    __syncthreads();
    #pragma unroll
    for (int s = 1; s < SCAN_B; s <<= 1) {
        int t = (threadIdx.x >= (unsigned)s) ? sm[threadIdx.x - s] : 0;
        __syncthreads();
        sm[threadIdx.x] += t;
        __syncthreads();
    }
    if (i < N) base[i] = sm[threadIdx.x] - v;   // exclusive
    if (threadIdx.x == SCAN_B - 1) bsum[blockIdx.x] = sm[threadIdx.x];
}

// ---------------------------------------------------------------------------
// Scan phase 2+3 fused: each block sums bsum[0..bid) itself, adds to base.
// ---------------------------------------------------------------------------
__global__ __launch_bounds__(SCAN_B) void scan23_kernel(
    int* __restrict__ base, const int* __restrict__ bsum, int N)
{
    int bid = blockIdx.x;
    int sum = 0;
    for (int t = (int)threadIdx.x; t < bid; t += SCAN_B) sum += bsum[t];
    #pragma unroll
    for (int s = 32; s > 0; s >>= 1) sum += __shfl_down(sum, s);
    __shared__ int ws[SCAN_B / 64];
    __shared__ int s_total;
    int lane = threadIdx.x & 63, wid = threadIdx.x >> 6;
    if (lane == 0) ws[wid] = sum;
    __syncthreads();
    if (threadIdx.x == 0) {
        int tot = 0;
        #pragma unroll
        for (int w = 0; w < SCAN_B / 64; ++w) tot += ws[w];
        s_total = tot;
    }
    __syncthreads();
    int i = bid * SCAN_B + threadIdx.x;
    if (i < N) base[i] += s_total;
}

// ---------------------------------------------------------------------------
// Kernel C: fused edge+node MLP via v_dot2_f32_f16 (round-8/13 proven,
// one edge per thread; VGPR 24, ~105 us, ~95% of dot2-issue ceiling).
// ---------------------------------------------------------------------------
__global__ __launch_bounds__(256, 4) void edge_mlp_fused_kernel(
    const float* __restrict__ x,
    const int*   __restrict__ ei,
    const float* __restrict__ ea,
    const h2* __restrict__ ew1pk, const float* __restrict__ eb1,
    const h2* __restrict__ ew2pk, const float* __restrict__ eb2,
    const h2* __restrict__ nw1pk, const float* __restrict__ nb1,
    const h2* __restrict__ nw2pk, const float* __restrict__ nb2,
    const int* __restrict__ base, const int* __restrict__ rank,
    unsigned int* __restrict__ hbuf16,
    int E)
{
    int e = blockIdx.x * blockDim.x + threadIdx.x;
    if (e >= E) return;

    int r = ei[e];
    int c = ei[E + e];
    int slot = base[r] + rank[e];

    float in9[9];
    in9[0] = x[3 * r + 0];
    in9[1] = x[3 * r + 1];
    in9[2] = x[3 * r + 2];
    in9[3] = x[3 * c + 0];
    in9[4] = x[3 * c + 1];
    in9[5] = x[3 * c + 2];
    in9[6] = ea[3 * (size_t)e + 0];
    in9[7] = ea[3 * (size_t)e + 1];
    in9[8] = ea[3 * (size_t)e + 2];

    h2 inpk[5];
    inpk[0] = pkrtz(in9[0], in9[1]);
    inpk[1] = pkrtz(in9[2], in9[3]);
    inpk[2] = pkrtz(in9[4], in9[5]);
    inpk[3] = pkrtz(in9[6], in9[7]);
    inpk[4] = pkrtz(in9[8], 0.0f);

    // edge MLP layer 1: 9 -> 50 (relu), kept packed
    h2 hpk[25];
    #pragma unroll
    for (int jj = 0; jj < 25; ++jj) {
        float a0 = eb1[2 * jj];
        float a1 = eb1[2 * jj + 1];
        #pragma unroll
        for (int p = 0; p < 5; ++p) {
            a0 = fdot2(inpk[p], ew1pk[(2 * jj) * 5 + p], a0);
            a1 = fdot2(inpk[p], ew1pk[(2 * jj + 1) * 5 + p], a1);
        }
        hpk[jj] = pkrtz(fmaxf(a0, 0.0f), fmaxf(a1, 0.0f));
    }

    // edge MLP layer 2: 50 -> 15
    float e2v[D3];
    #pragma unroll
    for (int m = 0; m < D3; ++m) {
        float a = eb2[m];
        #pragma unroll
        for (int k = 0; k < 25; ++k) a = fdot2(hpk[k], ew2pk[m * 25 + k], a);
        e2v[m] = a;
    }

    // node-MLP input: [xc(3), e2(15)] = 18 -> 9 pairs
    h2 vpk[9];
    vpk[0] = pkrtz(in9[3], in9[4]);
    vpk[1] = pkrtz(in9[5], e2v[0]);
    #pragma unroll
    for (int p = 2; p < 9; ++p) vpk[p] = pkrtz(e2v[2 * p - 3], e2v[2 * p - 2]);

    // node MLP layer 1: 18 -> 50 (relu), kept packed
    h2 h2pk[25];
    #pragma unroll
    for (int jj = 0; jj < 25; ++jj) {
        float a0 = nb1[2 * jj];
        float a1 = nb1[2 * jj + 1];
        #pragma unroll
        for (int p = 0; p < 9; ++p) {
            a0 = fdot2(vpk[p], nw1pk[(2 * jj) * 9 + p], a0);
            a1 = fdot2(vpk[p], nw1pk[(2 * jj + 1) * 9 + p], a1);
        }
        h2pk[jj] = pkrtz(fmaxf(a0, 0.0f), fmaxf(a1, 0.0f));
    }

    // node MLP layer 2: 50 -> 15, pack to f16, 32B store
    float acc[D3 + 1];
    #pragma unroll
    for (int m = 0; m < D3; ++m) {
        float a = nb2[m];
        #pragma unroll
        for (int k = 0; k < 25; ++k) a = fdot2(h2pk[k], nw2pk[m * 25 + k], a);
        acc[m] = a;
    }
    acc[D3] = 0.0f;

    union { h2 h[8]; uint4 u[2]; } outp;
    #pragma unroll
    for (int p = 0; p < 8; ++p) outp.h[p] = pkrtz(acc[2 * p], acc[2 * p + 1]);

    uint4* dst = (uint4*)(hbuf16 + (size_t)slot * 8);
    dst[0] = outp.u[0];
    dst[1] = outp.u[1];
}

// ---------------------------------------------------------------------------
// Kernel T: fused tail (round-9/13 proven). One block per graph.
// ---------------------------------------------------------------------------
__global__ __launch_bounds__(256) void tail_kernel(
    const unsigned int* __restrict__ hbuf16,
    const int* __restrict__ deg, const int* __restrict__ base,
    const int* __restrict__ batch, int N,
    const float* __restrict__ u,
    const float* __restrict__ gw1, const float* __restrict__ gb1,
    const float* __restrict__ gw2, const float* __restrict__ gb2,
    const float* __restrict__ fc1w, const float* __restrict__ fc1b,
    const float* __restrict__ bng, const float* __restrict__ bnb,
    const float* __restrict__ fc2w, const float* __restrict__ fc2b,
    float* __restrict__ out)
{
    int b = blockIdx.x;
    int tid = threadIdx.x;

    int lo = 0, hi = N;
    while (lo < hi) { int m = (lo + hi) >> 1; if (batch[m] < b) lo = m + 1; else hi = m; }
    int start = lo;
    hi = N;
    while (lo < hi) { int m = (lo + hi) >> 1; if (batch[m] < b + 1) lo = m + 1; else hi = m; }
    int end = lo;

    float sx[D3], sr[D3];
    #pragma unroll
    for (int j = 0; j < D3; ++j) { sx[j] = 0.0f; sr[j] = 0.0f; }

    for (int i = start + tid; i < end; i += 256) {
        int bs = base[i];
        int d  = deg[i];
        float acc[16];
        #pragma unroll
        for (int j = 0; j < 16; ++j) acc[j] = 0.0f;
        const uint4* ptr = (const uint4*)(hbuf16 + (size_t)bs * 8);
        for (int k = 0; k < d; ++k) {
            uint4 w0 = ptr[2 * k];
            uint4 w1 = ptr[2 * k + 1];
            unsigned int ws[8] = {w0.x, w0.y, w0.z, w0.w, w1.x, w1.y, w1.z, w1.w};
            #pragma unroll
            for (int p = 0; p < 8; ++p) {
                h2 v = __builtin_bit_cast(h2, ws[p]);
                acc[2 * p]     += (float)v[0];
                acc[2 * p + 1] += (float)v[1];
            }
        }
        float inv = 1.0f / fmaxf((float)d, 1.0f);
        #pragma unroll
        for (int j = 0; j < D3; ++j) {
            float v = acc[j] * inv;
            sx[j] += v;
            sr[j] += fmaxf(v, 0.0f);
        }
    }

    #pragma unroll
    for (int j = 0; j < D3; ++j) {
        #pragma unroll
        for (int s = 32; s > 0; s >>= 1) {
            sx[j] += __shfl_down(sx[j], s);
            sr[j] += __shfl_down(sr[j], s);
        }
    }

    __shared__ float sm[4][2 * D3];
    __shared__ float s_red[2 * D3];
    __shared__ float s_in16[16];
    __shared__ float s_gh[D2];
    __shared__ float s_g[D3];
    __shared__ float s_h1[D5];

    int lane = tid & 63, wid = tid >> 6;
    if (lane == 0) {
        #pragma unroll
        for (int j = 0; j < D3; ++j) { sm[wid][j] = sx[j]; sm[wid][D3 + j] = sr[j]; }
    }
    __syncthreads();

    float nct = (float)(end - start);

    if (tid < 2 * D3) {
        s_red[tid] = sm[0][tid] + sm[1][tid] + sm[2][tid] + sm[3][tid];
    }
    __syncthreads();

    if (tid < 16) {
        s_in16[tid] = (tid == 0) ? u[b] : s_red[tid - 1] / fmaxf(nct, 1.0f);
    }
    __syncthreads();

    if (tid < D2) {
        float a = gb1[tid];
        #pragma unroll
        for (int k = 0; k < 16; ++k) a = fmaf(s_in16[k], gw1[k * D2 + tid], a);
        s_gh[tid] = fmaxf(a, 0.0f);
    }
    __syncthreads();

    if (tid < D3) {
        float a = gb2[tid];
        #pragma unroll
        for (int k = 0; k < D2; ++k) a = fmaf(s_gh[k], gw2[k * D3 + tid], a);
        s_g[tid] = (s_red[D3 + tid] + fmaxf(a, 0.0f)) / (nct + 1.0f);
    }
    __syncthreads();

    if (tid < D5) {
        const float bnscale = 1.0f / sqrtf(1.0f + 1e-5f);
        float a = fc1b[tid];
        #pragma unroll
        for (int k = 0; k < D3; ++k) a = fmaf(s_g[k], fc1w[k * D5 + tid], a);
        s_h1[tid] = fmaxf(a * (bng[tid] * bnscale) + bnb[tid], 0.0f);
    }
    __syncthreads();

    if (tid == 0) {
        float o[NC];
        #pragma unroll
        for (int j = 0; j < NC; ++j) {
            float a = fc2b[j];
            #pragma unroll
            for (int k = 0; k < D5; ++k) a = fmaf(s_h1[k], fc2w[k * NC + j], a);
            o[j] = a;
        }
        float m = o[0];
        #pragma unroll
        for (int j = 1; j < NC; ++j) m = fmaxf(m, o[j]);
        float ssum = 0.0f;
        #pragma unroll
        for (int j = 0; j < NC; ++j) ssum += expf(o[j] - m);
        float lse = m + logf(ssum);
        #pragma unroll
        for (int j = 0; j < NC; ++j) out[b * NC + j] = o[j] - lse;
    }
}

// ---------------------------------------------------------------------------
// Fallback (round-1) kernels: atomic scatter-mean. Used only if ws too small.
// ---------------------------------------------------------------------------
__global__ __launch_bounds__(256) void edge_node_atomic_kernel(
    const float* __restrict__ x,
    const int*   __restrict__ ei,
    const float* __restrict__ ea,
    const float* __restrict__ ew1, const float* __restrict__ eb1,
    const float* __restrict__ ew2, const float* __restrict__ eb2,
    const float* __restrict__ nw1, const float* __restrict__ nb1,
    const float* __restrict__ nw2, const float* __restrict__ nb2,
    float* __restrict__ x2sum, float* __restrict__ cnt,
    int E)
{
    int e = blockIdx.x * blockDim.x + threadIdx.x;
    if (e >= E) return;
    int r = ei[e];
    int c = ei[E + e];
    float in9[9];
    in9[0] = x[3 * r + 0]; in9[1] = x[3 * r + 1]; in9[2] = x[3 * r + 2];
    float xc0 = x[3 * c + 0], xc1 = x[3 * c + 1], xc2 = x[3 * c + 2];
    in9[3] = xc0; in9[4] = xc1; in9[5] = xc2;
    in9[6] = ea[3 * e + 0]; in9[7] = ea[3 * e + 1]; in9[8] = ea[3 * e + 2];
    float h[D2];
    #pragma unroll
    for (int j = 0; j < D2; ++j) {
        float a = eb1[j];
        #pragma unroll
        for (int k = 0; k < 9; ++k) a = fmaf(in9[k], ew1[k * D2 + j], a);
        h[j] = fmaxf(a, 0.0f);
    }
    float e2[D3];
    #pragma unroll
    for (int j = 0; j < D3; ++j) {
        float a = eb2[j];
        #pragma unroll
        for (int k = 0; k < D2; ++k) a = fmaf(h[k], ew2[k * D3 + j], a);
        e2[j] = a;
    }
    float h2v[D2];
    #pragma unroll
    for (int j = 0; j < D2; ++j) {
        float a = nb1[j];
        a = fmaf(xc0, nw1[0 * D2 + j], a);
        a = fmaf(xc1, nw1[1 * D2 + j], a);
        a = fmaf(xc2, nw1[2 * D2 + j], a);
        #pragma unroll
        for (int k = 0; k < D3; ++k) a = fmaf(e2[k], nw1[(3 + k) * D2 + j], a);
        h2v[j] = fmaxf(a, 0.0f);
    }
    float* dst = x2sum + (size_t)r * D3;
    #pragma unroll
    for (int j = 0; j < D3; ++j) {
        float a = nb2[j];
        #pragma unroll
        for (int k = 0; k < D2; ++k) a = fmaf(h2v[k], nw2[k * D3 + j], a);
        atomicAdd(&dst[j], a);
    }
    atomicAdd(&cnt[r], 1.0f);
}

__global__ __launch_bounds__(256) void graph_sum_atomic_kernel(
    const float* __restrict__ x2sum, const float* __restrict__ cnt,
    const int* __restrict__ batch, int N,
    float* __restrict__ bx, float* __restrict__ brelu, float* __restrict__ ncnt)
{
    int b = blockIdx.x;
    int lo = 0, hi = N;
    while (lo < hi) { int m = (lo + hi) >> 1; if (batch[m] < b) lo = m + 1; else hi = m; }
    int start = lo;
    hi = N;
    while (lo < hi) { int m = (lo + hi) >> 1; if (batch[m] < b + 1) lo = m + 1; else hi = m; }
    int end = lo;
    float sx[D3], sr[D3];
    #pragma unroll
    for (int j = 0; j < D3; ++j) { sx[j] = 0.0f; sr[j] = 0.0f; }
    for (int i = start + (int)threadIdx.x; i < end; i += (int)blockDim.x) {
        float inv = 1.0f / fmaxf(cnt[i], 1.0f);
        #pragma unroll
        for (int j = 0; j < D3; ++j) {
            float v = x2sum[(size_t)i * D3 + j] * inv;
            sx[j] += v;
            sr[j] += fmaxf(v, 0.0f);
        }
    }
    #pragma unroll
    for (int j = 0; j < D3; ++j) {
        #pragma unroll
        for (int s = 32; s > 0; s >>= 1) {
            sx[j] += __shfl_down(sx[j], s);
            sr[j] += __shfl_down(sr[j], s);
        }
    }
    __shared__ float sm[4][2 * D3];
    int lane = threadIdx.x & 63, wid = threadIdx.x >> 6;
    if (lane == 0) {
        #pragma unroll
        for (int j = 0; j < D3; ++j) { sm[wid][j] = sx[j]; sm[wid][D3 + j] = sr[j]; }
    }
    __syncthreads();
    if (threadIdx.x < 2 * D3) {
        float v = sm[0][threadIdx.x] + sm[1][threadIdx.x] + sm[2][threadIdx.x] + sm[3][threadIdx.x];
        if (threadIdx.x < D3) bx[b * D3 + threadIdx.x] = v;
        else                  brelu[b * D3 + (threadIdx.x - D3)] = v;
    }
    if (threadIdx.x == 0) ncnt[b] = (float)(end - start);
}

__global__ __launch_bounds__(256) void final_kernel(
    const float* __restrict__ u,
    const float* __restrict__ gw1, const float* __restrict__ gb1,
    const float* __restrict__ gw2, const float* __restrict__ gb2,
    const float* __restrict__ fc1w, const float* __restrict__ fc1b,
    const float* __restrict__ bng, const float* __restrict__ bnb,
    const float* __restrict__ fc2w, const float* __restrict__ fc2b,
    const float* __restrict__ bx, const float* __restrict__ brelu,
    const float* __restrict__ ncnt,
    float* __restrict__ out, int B)
{
    int t = blockIdx.x * blockDim.x + threadIdx.x;
    if (t >= B) return;
    float nct = ncnt[t];
    float inv = 1.0f / fmaxf(nct, 1.0f);
    float in16[16];
    in16[0] = u[t];
    #pragma unroll
    for (int j = 0; j < D3; ++j) in16[1 + j] = bx[t * D3 + j] * inv;
    float gh[D2];
    #pragma unroll
    for (int j = 0; j < D2; ++j) {
        float a = gb1[j];
        #pragma unroll
        for (int k = 0; k < 16; ++k) a = fmaf(in16[k], gw1[k * D2 + j], a);
        gh[j] = fmaxf(a, 0.0f);
    }
    float g[D3];
    #pragma unroll
    for (int j = 0; j < D3; ++j) {
        float a = gb2[j];
        #pragma unroll
        for (int k = 0; k < D2; ++k) a = fmaf(gh[k], gw2[k * D3 + j], a);
        g[j] = (brelu[t * D3 + j] + fmaxf(a, 0.0f)) / (nct + 1.0f);
    }
    const float bnscale = 1.0f / sqrtf(1.0f + 1e-5f);
    float h1[D5];
    #pragma unroll
    for (int i = 0; i < D5; ++i) {
        float a = fc1b[i];
        #pragma unroll
        for (int k = 0; k < D3; ++k) a = fmaf(g[k], fc1w[k * D5 + i], a);
        h1[i] = fmaxf(a * (bng[i] * bnscale) + bnb[i], 0.0f);
    }
    float o[NC];
    #pragma unroll
    for (int j = 0; j < NC; ++j) {
        float a = fc2b[j];
        #pragma unroll
        for (int k = 0; k < D5; ++k) a = fmaf(h1[k], fc2w[k * NC + j], a);
        o[j] = a;
    }
    float m = o[0];
    #pragma unroll
    for (int j = 1; j < NC; ++j) m = fmaxf(m, o[j]);
    float ssum = 0.0f;
    #pragma unroll
    for (int j = 0; j < NC; ++j) ssum += expf(o[j] - m);
    float lse = m + logf(ssum);
    #pragma unroll
    for (int j = 0; j < NC; ++j) out[t * NC + j] = o[j] - lse;
}

extern "C" void kernel_launch(void* const* d_in, const int* in_sizes, int n_in,
                              void* d_out, int out_size, void* d_ws, size_t ws_size,
                              hipStream_t stream) {
    const float* x     = (const float*)d_in[0];
    const int*   ei    = (const int*)  d_in[1];
    const float* ea    = (const float*)d_in[2];
    const float* u     = (const float*)d_in[3];
    const int*   batch = (const int*)  d_in[4];
    const float* ew1 = (const float*)d_in[5];
    const float* eb1 = (const float*)d_in[6];
    const float* ew2 = (const float*)d_in[7];
    const float* eb2 = (const float*)d_in[8];
    const float* nw1 = (const float*)d_in[9];
    const float* nb1 = (const float*)d_in[10];
    const float* nw2 = (const float*)d_in[11];
    const float* nb2 = (const float*)d_in[12];
    const float* gw1 = (const float*)d_in[13];
    const float* gb1 = (const float*)d_in[14];
    const float* gw2 = (const float*)d_in[15];
    const float* gb2 = (const float*)d_in[16];
    const float* fc1w = (const float*)d_in[17];
    const float* fc1b = (const float*)d_in[18];
    const float* bng  = (const float*)d_in[19];
    const float* bnb  = (const float*)d_in[20];
    const float* fc2w = (const float*)d_in[21];
    const float* fc2b = (const float*)d_in[22];

    int N = in_sizes[0] / 3;
    int E = in_sizes[2] / 3;
    int B = in_sizes[3];
    float* out = (float*)d_out;

    int nsb = (N + SCAN_B - 1) / SCAN_B;   // scan blocks (196 for N=100K)
    const size_t WPK = 2048;               // packed weights (h2), padded

    size_t need = sizeof(h2) * WPK
                + sizeof(unsigned int) * (size_t)E * 8                 /* hbuf16 */
                + sizeof(int) * ((size_t)N + (size_t)E + (size_t)N + 1024);

    if (ws_size >= need && nsb <= 1024) {
        // ---- fast path: CSR build + packed-f16 dot2 MLP + fused tail ----
        char* p = (char*)d_ws;
        h2* ew1pk = (h2*)p;                 // 250
        h2* nw1pk = ew1pk + 250;            // 450
        h2* ew2pk = nw1pk + 450;            // 375
        h2* nw2pk = ew2pk + 375;            // 375
        p += sizeof(h2) * WPK;
        unsigned int* hbuf16 = (unsigned int*)p;  p += sizeof(unsigned int) * (size_t)E * 8;
        int* deg  = (int*)p;            p += sizeof(int) * (size_t)N;
        int* rank = (int*)p;            p += sizeof(int) * (size_t)E;
        int* base = (int*)p;            p += sizeof(int) * (size_t)N;
        int* bsum = (int*)p;            p += sizeof(int) * 1024;

        hipMemsetAsync(deg, 0, sizeof(int) * (size_t)N, stream);

        int eb = (E + 255) / 256;
        deg_rank_prep_kernel<<<eb, 256, 0, stream>>>(
            ei, deg, rank, E, ew1, nw1, ew2, nw2, ew1pk, nw1pk, ew2pk, nw2pk);

        scan1_kernel<<<nsb, SCAN_B, 0, stream>>>(deg, base, bsum, N);
        scan23_kernel<<<nsb, SCAN_B, 0, stream>>>(base, bsum, N);

        edge_mlp_fused_kernel<<<eb, 256, 0, stream>>>(
            x, ei, ea, ew1pk, eb1, ew2pk, eb2, nw1pk, nb1, nw2pk, nb2,
            base, rank, hbuf16, E);

        tail_kernel<<<B, 256, 0, stream>>>(
            hbuf16, deg, base, batch, N,
            u, gw1, gb1, gw2, gb2, fc1w, fc1b, bng, bnb, fc2w, fc2b, out);
    } else {
        // ---- fallback: round-1 atomic path (fp32 exact) ----
        float* x2sum = (float*)d_ws;
        float* cnt   = x2sum + (size_t)N * D3;
        float* bx    = cnt + N;
        float* brelu = bx + (size_t)B * D3;
        float* ncnt  = brelu + (size_t)B * D3;

        hipMemsetAsync(x2sum, 0, sizeof(float) * ((size_t)N * D3 + N), stream);

        int eb = (E + 255) / 256;
        edge_node_atomic_kernel<<<eb, 256, 0, stream>>>(
            x, ei, ea, ew1, eb1, ew2, eb2, nw1, nb1, nw2, nb2, x2sum, cnt, E);

        graph_sum_atomic_kernel<<<B, 256, 0, stream>>>(x2sum, cnt, batch, N, bx, brelu, ncnt);

        int fb = (B + 255) / 256;
        final_kernel<<<fb, 256, 0, stream>>>(
            u, gw1, gb1, gw2, gb2, fc1w, fc1b, bng, bnb, fc2w, fc2b,
            bx, brelu, ncnt, out, B);
    }
}

// Round 18
// 205.323 us; speedup vs baseline: 1.1060x; 1.0084x over previous
//
#include <hip/hip_runtime.h>
#include <math.h>

#define D1 3
#define D2 50
#define D3 15
#define D5 10
#define NC 6
#define SCAN_B 512

typedef _Float16 h2 __attribute__((ext_vector_type(2)));
typedef __fp16   fp16x2 __attribute__((ext_vector_type(2)));

__device__ __forceinline__ float fdot2(h2 a, h2 b, float c) {
#if __has_builtin(__builtin_amdgcn_fdot2)
    return __builtin_amdgcn_fdot2(a, b, c, false);
#else
    return c + (float)a[0] * (float)b[0] + (float)a[1] * (float)b[1];
#endif
}

__device__ __forceinline__ h2 pkrtz(float a, float b) {
#if __has_builtin(__builtin_amdgcn_cvt_pkrtz)
    fp16x2 r = __builtin_amdgcn_cvt_pkrtz(a, b);
    return __builtin_bit_cast(h2, r);
#else
    h2 v; v[0] = (_Float16)a; v[1] = (_Float16)b; return v;
#endif
}

// ---------------------------------------------------------------------------
// Kernel A: degree + rank (one int atomic per edge). Block 0 also packs the
// MLP weights into f16 pairs.
// ---------------------------------------------------------------------------
__global__ __launch_bounds__(256) void deg_rank_prep_kernel(
    const int* __restrict__ ei, int* __restrict__ deg, int* __restrict__ rank, int E,
    const float* __restrict__ ew1, const float* __restrict__ nw1,
    const float* __restrict__ ew2, const float* __restrict__ nw2,
    h2* __restrict__ ew1pk, h2* __restrict__ nw1pk,
    h2* __restrict__ ew2pk, h2* __restrict__ nw2pk)
{
    int e = blockIdx.x * blockDim.x + threadIdx.x;
    if (e < E) {
        int r = ei[e];
        rank[e] = atomicAdd(&deg[r], 1);
    }
    if (blockIdx.x == 0) {
        int t = threadIdx.x;
        for (int i = t; i < D2 * 5; i += 256) {
            int j = i / 5, p = i - 5 * j;
            float a = ew1[(2 * p) * D2 + j];
            float b = (2 * p + 1 < 9) ? ew1[(2 * p + 1) * D2 + j] : 0.0f;
            h2 v; v[0] = (_Float16)a; v[1] = (_Float16)b;
            ew1pk[i] = v;
        }
        for (int i = t; i < D2 * 9; i += 256) {
            int j = i / 9, p = i - 9 * j;
            float a = nw1[(2 * p) * D2 + j];
            float b = nw1[(2 * p + 1) * D2 + j];
            h2 v; v[0] = (_Float16)a; v[1] = (_Float16)b;
            nw1pk[i] = v;
        }
        for (int i = t; i < D3 * 25; i += 256) {
            int m = i / 25, k = i - 25 * m;
            float a = ew2[(2 * k) * D3 + m];
            float b = ew2[(2 * k + 1) * D3 + m];
            h2 v; v[0] = (_Float16)a; v[1] = (_Float16)b;
            ew2pk[i] = v;
            float c = nw2[(2 * k) * D3 + m];
            float d = nw2[(2 * k + 1) * D3 + m];
            h2 w; w[0] = (_Float16)c; w[1] = (_Float16)d;
            nw2pk[i] = w;
        }
    }
}

// ---------------------------------------------------------------------------
// Scan phase 1: per-block inclusive scan of deg -> exclusive base + block sums.
// ---------------------------------------------------------------------------
__global__ __launch_bounds__(SCAN_B) void scan1_kernel(
    const int* __restrict__ deg, int* __restrict__ base, int* __restrict__ bsum, int N)
{
    __shared__ int sm[SCAN_B];
    int i = blockIdx.x * SCAN_B + threadIdx.x;
    int v = (i < N) ? deg[i] : 0;
    sm[threadIdx.x] = v;
    __syncthreads();
    #pragma unroll
    for (int s = 1; s < SCAN_B; s <<= 1) {
        int t = (threadIdx.x >= (unsigned)s) ? sm[threadIdx.x - s] : 0;
        __syncthreads();
        sm[threadIdx.x] += t;
        __syncthreads();
    }
    if (i < N) base[i] = sm[threadIdx.x] - v;   // exclusive
    if (threadIdx.x == SCAN_B - 1) bsum[blockIdx.x] = sm[threadIdx.x];
}

// ---------------------------------------------------------------------------
// Scan phase 2+3 fused: each block sums bsum[0..bid) itself, adds to base.
// ---------------------------------------------------------------------------
__global__ __launch_bounds__(SCAN_B) void scan23_kernel(
    int* __restrict__ base, const int* __restrict__ bsum, int N)
{
    int bid = blockIdx.x;
    int sum = 0;
    for (int t = (int)threadIdx.x; t < bid; t += SCAN_B) sum += bsum[t];
    #pragma unroll
    for (int s = 32; s > 0; s >>= 1) sum += __shfl_down(sum, s);
    __shared__ int ws[SCAN_B / 64];
    __shared__ int s_total;
    int lane = threadIdx.x & 63, wid = threadIdx.x >> 6;
    if (lane == 0) ws[wid] = sum;
    __syncthreads();
    if (threadIdx.x == 0) {
        int tot = 0;
        #pragma unroll
        for (int w = 0; w < SCAN_B / 64; ++w) tot += ws[w];
        s_total = tot;
    }
    __syncthreads();
    int i = bid * SCAN_B + threadIdx.x;
    if (i < N) base[i] += s_total;
}

// ---------------------------------------------------------------------------
// Kernel C: fused edge+node MLP via v_dot2_f32_f16 (round-8/13 proven,
// one edge per thread; VGPR 24, ~105 us, ~95% of dot2-issue ceiling).
// ---------------------------------------------------------------------------
__global__ __launch_bounds__(256, 4) void edge_mlp_fused_kernel(
    const float* __restrict__ x,
    const int*   __restrict__ ei,
    const float* __restrict__ ea,
    const h2* __restrict__ ew1pk, const float* __restrict__ eb1,
    const h2* __restrict__ ew2pk, const float* __restrict__ eb2,
    const h2* __restrict__ nw1pk, const float* __restrict__ nb1,
    const h2* __restrict__ nw2pk, const float* __restrict__ nb2,
    const int* __restrict__ base, const int* __restrict__ rank,
    unsigned int* __restrict__ hbuf16,
    int E)
{
    int e = blockIdx.x * blockDim.x + threadIdx.x;
    if (e >= E) return;

    int r = ei[e];
    int c = ei[E + e];
    int slot = base[r] + rank[e];

    float in9[9];
    in9[0] = x[3 * r + 0];
    in9[1] = x[3 * r + 1];
    in9[2] = x[3 * r + 2];
    in9[3] = x[3 * c + 0];
    in9[4] = x[3 * c + 1];
    in9[5] = x[3 * c + 2];
    in9[6] = ea[3 * (size_t)e + 0];
    in9[7] = ea[3 * (size_t)e + 1];
    in9[8] = ea[3 * (size_t)e + 2];

    h2 inpk[5];
    inpk[0] = pkrtz(in9[0], in9[1]);
    inpk[1] = pkrtz(in9[2], in9[3]);
    inpk[2] = pkrtz(in9[4], in9[5]);
    inpk[3] = pkrtz(in9[6], in9[7]);
    inpk[4] = pkrtz(in9[8], 0.0f);

    // edge MLP layer 1: 9 -> 50 (relu), kept packed
    h2 hpk[25];
    #pragma unroll
    for (int jj = 0; jj < 25; ++jj) {
        float a0 = eb1[2 * jj];
        float a1 = eb1[2 * jj + 1];
        #pragma unroll
        for (int p = 0; p < 5; ++p) {
            a0 = fdot2(inpk[p], ew1pk[(2 * jj) * 5 + p], a0);
            a1 = fdot2(inpk[p], ew1pk[(2 * jj + 1) * 5 + p], a1);
        }
        hpk[jj] = pkrtz(fmaxf(a0, 0.0f), fmaxf(a1, 0.0f));
    }

    // edge MLP layer 2: 50 -> 15
    float e2v[D3];
    #pragma unroll
    for (int m = 0; m < D3; ++m) {
        float a = eb2[m];
        #pragma unroll
        for (int k = 0; k < 25; ++k) a = fdot2(hpk[k], ew2pk[m * 25 + k], a);
        e2v[m] = a;
    }

    // node-MLP input: [xc(3), e2(15)] = 18 -> 9 pairs
    h2 vpk[9];
    vpk[0] = pkrtz(in9[3], in9[4]);
    vpk[1] = pkrtz(in9[5], e2v[0]);
    #pragma unroll
    for (int p = 2; p < 9; ++p) vpk[p] = pkrtz(e2v[2 * p - 3], e2v[2 * p - 2]);

    // node MLP layer 1: 18 -> 50 (relu), kept packed
    h2 h2pk[25];
    #pragma unroll
    for (int jj = 0; jj < 25; ++jj) {
        float a0 = nb1[2 * jj];
        float a1 = nb1[2 * jj + 1];
        #pragma unroll
        for (int p = 0; p < 9; ++p) {
            a0 = fdot2(vpk[p], nw1pk[(2 * jj) * 9 + p], a0);
            a1 = fdot2(vpk[p], nw1pk[(2 * jj + 1) * 9 + p], a1);
        }
        h2pk[jj] = pkrtz(fmaxf(a0, 0.0f), fmaxf(a1, 0.0f));
    }

    // node MLP layer 2: 50 -> 15, pack to f16, 32B store
    float acc[D3 + 1];
    #pragma unroll
    for (int m = 0; m < D3; ++m) {
        float a = nb2[m];
        #pragma unroll
        for (int k = 0; k < 25; ++k) a = fdot2(h2pk[k], nw2pk[m * 25 + k], a);
        acc[m] = a;
    }
    acc[D3] = 0.0f;

    union { h2 h[8]; uint4 u[2]; } outp;
    #pragma unroll
    for (int p = 0; p < 8; ++p) outp.h[p] = pkrtz(acc[2 * p], acc[2 * p + 1]);

    uint4* dst = (uint4*)(hbuf16 + (size_t)slot * 8);
    dst[0] = outp.u[0];
    dst[1] = outp.u[1];
}

// ---------------------------------------------------------------------------
// Kernel T: fused tail (round-9/13 proven). One block per graph.
// ---------------------------------------------------------------------------
__global__ __launch_bounds__(256) void tail_kernel(
    const unsigned int* __restrict__ hbuf16,
    const int* __restrict__ deg, const int* __restrict__ base,
    const int* __restrict__ batch, int N,
    const float* __restrict__ u,
    const float* __restrict__ gw1, const float* __restrict__ gb1,
    const float* __restrict__ gw2, const float* __restrict__ gb2,
    const float* __restrict__ fc1w, const float* __restrict__ fc1b,
    const float* __restrict__ bng, const float* __restrict__ bnb,
    const float* __restrict__ fc2w, const float* __restrict__ fc2b,
    float* __restrict__ out)
{
    int b = blockIdx.x;
    int tid = threadIdx.x;

    int lo = 0, hi = N;
    while (lo < hi) { int m = (lo + hi) >> 1; if (batch[m] < b) lo = m + 1; else hi = m; }
    int start = lo;
    hi = N;
    while (lo < hi) { int m = (lo + hi) >> 1; if (batch[m] < b + 1) lo = m + 1; else hi = m; }
    int end = lo;

    float sx[D3], sr[D3];
    #pragma unroll
    for (int j = 0; j < D3; ++j) { sx[j] = 0.0f; sr[j] = 0.0f; }

    for (int i = start + tid; i < end; i += 256) {
        int bs = base[i];
        int d  = deg[i];
        float acc[16];
        #pragma unroll
        for (int j = 0; j < 16; ++j) acc[j] = 0.0f;
        const uint4* ptr = (const uint4*)(hbuf16 + (size_t)bs * 8);
        for (int k = 0; k < d; ++k) {
            uint4 w0 = ptr[2 * k];
            uint4 w1 = ptr[2 * k + 1];
            unsigned int ws[8] = {w0.x, w0.y, w0.z, w0.w, w1.x, w1.y, w1.z, w1.w};
            #pragma unroll
            for (int p = 0; p < 8; ++p) {
                h2 v = __builtin_bit_cast(h2, ws[p]);
                acc[2 * p]     += (float)v[0];
                acc[2 * p + 1] += (float)v[1];
            }
        }
        float inv = 1.0f / fmaxf((float)d, 1.0f);
        #pragma unroll
        for (int j = 0; j < D3; ++j) {
            float v = acc[j] * inv;
            sx[j] += v;
            sr[j] += fmaxf(v, 0.0f);
        }
    }

    #pragma unroll
    for (int j = 0; j < D3; ++j) {
        #pragma unroll
        for (int s = 32; s > 0; s >>= 1) {
            sx[j] += __shfl_down(sx[j], s);
            sr[j] += __shfl_down(sr[j], s);
        }
    }

    __shared__ float sm[4][2 * D3];
    __shared__ float s_red[2 * D3];
    __shared__ float s_in16[16];
    __shared__ float s_gh[D2];
    __shared__ float s_g[D3];
    __shared__ float s_h1[D5];

    int lane = tid & 63, wid = tid >> 6;
    if (lane == 0) {
        #pragma unroll
        for (int j = 0; j < D3; ++j) { sm[wid][j] = sx[j]; sm[wid][D3 + j] = sr[j]; }
    }
    __syncthreads();

    float nct = (float)(end - start);

    if (tid < 2 * D3) {
        s_red[tid] = sm[0][tid] + sm[1][tid] + sm[2][tid] + sm[3][tid];
    }
    __syncthreads();

    if (tid < 16) {
        s_in16[tid] = (tid == 0) ? u[b] : s_red[tid - 1] / fmaxf(nct, 1.0f);
    }
    __syncthreads();

    if (tid < D2) {
        float a = gb1[tid];
        #pragma unroll
        for (int k = 0; k < 16; ++k) a = fmaf(s_in16[k], gw1[k * D2 + tid], a);
        s_gh[tid] = fmaxf(a, 0.0f);
    }
    __syncthreads();

    if (tid < D3) {
        float a = gb2[tid];
        #pragma unroll
        for (int k = 0; k < D2; ++k) a = fmaf(s_gh[k], gw2[k * D3 + tid], a);
        s_g[tid] = (s_red[D3 + tid] + fmaxf(a, 0.0f)) / (nct + 1.0f);
    }
    __syncthreads();

    if (tid < D5) {
        const float bnscale = 1.0f / sqrtf(1.0f + 1e-5f);
        float a = fc1b[tid];
        #pragma unroll
        for (int k = 0; k < D3; ++k) a = fmaf(s_g[k], fc1w[k * D5 + tid], a);
        s_h1[tid] = fmaxf(a * (bng[tid] * bnscale) + bnb[tid], 0.0f);
    }
    __syncthreads();

    if (tid == 0) {
        float o[NC];
        #pragma unroll
        for (int j = 0; j < NC; ++j) {
            float a = fc2b[j];
            #pragma unroll
            for (int k = 0; k < D5; ++k) a = fmaf(s_h1[k], fc2w[k * NC + j], a);
            o[j] = a;
        }
        float m = o[0];
        #pragma unroll
        for (int j = 1; j < NC; ++j) m = fmaxf(m, o[j]);
        float ssum = 0.0f;
        #pragma unroll
        for (int j = 0; j < NC; ++j) ssum += expf(o[j] - m);
        float lse = m + logf(ssum);
        #pragma unroll
        for (int j = 0; j < NC; ++j) out[b * NC + j] = o[j] - lse;
    }
}

// ---------------------------------------------------------------------------
// Fallback (round-1) kernels: atomic scatter-mean. Used only if ws too small.
// ---------------------------------------------------------------------------
__global__ __launch_bounds__(256) void edge_node_atomic_kernel(
    const float* __restrict__ x,
    const int*   __restrict__ ei,
    const float* __restrict__ ea,
    const float* __restrict__ ew1, const float* __restrict__ eb1,
    const float* __restrict__ ew2, const float* __restrict__ eb2,
    const float* __restrict__ nw1, const float* __restrict__ nb1,
    const float* __restrict__ nw2, const float* __restrict__ nb2,
    float* __restrict__ x2sum, float* __restrict__ cnt,
    int E)
{
    int e = blockIdx.x * blockDim.x + threadIdx.x;
    if (e >= E) return;
    int r = ei[e];
    int c = ei[E + e];
    float in9[9];
    in9[0] = x[3 * r + 0]; in9[1] = x[3 * r + 1]; in9[2] = x[3 * r + 2];
    float xc0 = x[3 * c + 0], xc1 = x[3 * c + 1], xc2 = x[3 * c + 2];
    in9[3] = xc0; in9[4] = xc1; in9[5] = xc2;
    in9[6] = ea[3 * e + 0]; in9[7] = ea[3 * e + 1]; in9[8] = ea[3 * e + 2];
    float h[D2];
    #pragma unroll
    for (int j = 0; j < D2; ++j) {
        float a = eb1[j];
        #pragma unroll
        for (int k = 0; k < 9; ++k) a = fmaf(in9[k], ew1[k * D2 + j], a);
        h[j] = fmaxf(a, 0.0f);
    }
    float e2[D3];
    #pragma unroll
    for (int j = 0; j < D3; ++j) {
        float a = eb2[j];
        #pragma unroll
        for (int k = 0; k < D2; ++k) a = fmaf(h[k], ew2[k * D3 + j], a);
        e2[j] = a;
    }
    float h2v[D2];
    #pragma unroll
    for (int j = 0; j < D2; ++j) {
        float a = nb1[j];
        a = fmaf(xc0, nw1[0 * D2 + j], a);
        a = fmaf(xc1, nw1[1 * D2 + j], a);
        a = fmaf(xc2, nw1[2 * D2 + j], a);
        #pragma unroll
        for (int k = 0; k < D3; ++k) a = fmaf(e2[k], nw1[(3 + k) * D2 + j], a);
        h2v[j] = fmaxf(a, 0.0f);
    }
    float* dst = x2sum + (size_t)r * D3;
    #pragma unroll
    for (int j = 0; j < D3; ++j) {
        float a = nb2[j];
        #pragma unroll
        for (int k = 0; k < D2; ++k) a = fmaf(h2v[k], nw2[k * D3 + j], a);
        atomicAdd(&dst[j], a);
    }
    atomicAdd(&cnt[r], 1.0f);
}

__global__ __launch_bounds__(256) void graph_sum_atomic_kernel(
    const float* __restrict__ x2sum, const float* __restrict__ cnt,
    const int* __restrict__ batch, int N,
    float* __restrict__ bx, float* __restrict__ brelu, float* __restrict__ ncnt)
{
    int b = blockIdx.x;
    int lo = 0, hi = N;
    while (lo < hi) { int m = (lo + hi) >> 1; if (batch[m] < b) lo = m + 1; else hi = m; }
    int start = lo;
    hi = N;
    while (lo < hi) { int m = (lo + hi) >> 1; if (batch[m] < b + 1) lo = m + 1; else hi = m; }
    int end = lo;
    float sx[D3], sr[D3];
    #pragma unroll
    for (int j = 0; j < D3; ++j) { sx[j] = 0.0f; sr[j] = 0.0f; }
    for (int i = start + (int)threadIdx.x; i < end; i += (int)blockDim.x) {
        float inv = 1.0f / fmaxf(cnt[i], 1.0f);
        #pragma unroll
        for (int j = 0; j < D3; ++j) {
            float v = x2sum[(size_t)i * D3 + j] * inv;
            sx[j] += v;
            sr[j] += fmaxf(v, 0.0f);
        }
    }
    #pragma unroll
    for (int j = 0; j < D3; ++j) {
        #pragma unroll
        for (int s = 32; s > 0; s >>= 1) {
            sx[j] += __shfl_down(sx[j], s);
            sr[j] += __shfl_down(sr[j], s);
        }
    }
    __shared__ float sm[4][2 * D3];
    int lane = threadIdx.x & 63, wid = threadIdx.x >> 6;
    if (lane == 0) {
        #pragma unroll
        for (int j = 0; j < D3; ++j) { sm[wid][j] = sx[j]; sm[wid][D3 + j] = sr[j]; }
    }
    __syncthreads();
    if (threadIdx.x < 2 * D3) {
        float v = sm[0][threadIdx.x] + sm[1][threadIdx.x] + sm[2][threadIdx.x] + sm[3][threadIdx.x];
        if (threadIdx.x < D3) bx[b * D3 + threadIdx.x] = v;
        else                  brelu[b * D3 + (threadIdx.x - D3)] = v;
    }
    if (threadIdx.x == 0) ncnt[b] = (float)(end - start);
}

__global__ __launch_bounds__(256) void final_kernel(
    const float* __restrict__ u,
    const float* __restrict__ gw1, const float* __restrict__ gb1,
    const float* __restrict__ gw2, const float* __restrict__ gb2,
    const float* __restrict__ fc1w, const float* __restrict__ fc1b,
    const float* __restrict__ bng, const float* __restrict__ bnb,
    const float* __restrict__ fc2w, const float* __restrict__ fc2b,
    const float* __restrict__ bx, const float* __restrict__ brelu,
    const float* __restrict__ ncnt,
    float* __restrict__ out, int B)
{
    int t = blockIdx.x * blockDim.x + threadIdx.x;
    if (t >= B) return;
    float nct = ncnt[t];
    float inv = 1.0f / fmaxf(nct, 1.0f);
    float in16[16];
    in16[0] = u[t];
    #pragma unroll
    for (int j = 0; j < D3; ++j) in16[1 + j] = bx[t * D3 + j] * inv;
    float gh[D2];
    #pragma unroll
    for (int j = 0; j < D2; ++j) {
        float a = gb1[j];
        #pragma unroll
        for (int k = 0; k < 16; ++k) a = fmaf(in16[k], gw1[k * D2 + j], a);
        gh[j] = fmaxf(a, 0.0f);
    }
    float g[D3];
    #pragma unroll
    for (int j = 0; j < D3; ++j) {
        float a = gb2[j];
        #pragma unroll
        for (int k = 0; k < D2; ++k) a = fmaf(gh[k], gw2[k * D3 + j], a);
        g[j] = (brelu[t * D3 + j] + fmaxf(a, 0.0f)) / (nct + 1.0f);
    }
    const float bnscale = 1.0f / sqrtf(1.0f + 1e-5f);
    float h1[D5];
    #pragma unroll
    for (int i = 0; i < D5; ++i) {
        float a = fc1b[i];
        #pragma unroll
        for (int k = 0; k < D3; ++k) a = fmaf(g[k], fc1w[k * D5 + i], a);
        h1[i] = fmaxf(a * (bng[i] * bnscale) + bnb[i], 0.0f);
    }
    float o[NC];
    #pragma unroll
    for (int j = 0; j < NC; ++j) {
        float a = fc2b[j];
        #pragma unroll
        for (int k = 0; k < D5; ++k) a = fmaf(h1[k], fc2w[k * NC + j], a);
        o[j] = a;
    }
    float m = o[0];
    #pragma unroll
    for (int j = 1; j < NC; ++j) m = fmaxf(m, o[j]);
    float ssum = 0.0f;
    #pragma unroll
    for (int j = 0; j < NC; ++j) ssum += expf(o[j] - m);
    float lse = m + logf(ssum);
    #pragma unroll
    for (int j = 0; j < NC; ++j) out[t * NC + j] = o[j] - lse;
}

extern "C" void kernel_launch(void* const* d_in, const int* in_sizes, int n_in,
                              void* d_out, int out_size, void* d_ws, size_t ws_size,
                              hipStream_t stream) {
    const float* x     = (const float*)d_in[0];
    const int*   ei    = (const int*)  d_in[1];
    const float* ea    = (const float*)d_in[2];
    const float* u     = (const float*)d_in[3];
    const int*   batch = (const int*)  d_in[4];
    const float* ew1 = (const float*)d_in[5];
    const float* eb1 = (const float*)d_in[6];
    const float* ew2 = (const float*)d_in[7];
    const float* eb2 = (const float*)d_in[8];
    const float* nw1 = (const float*)d_in[9];
    const float* nb1 = (const float*)d_in[10];
    const float* nw2 = (const float*)d_in[11];
    const float* nb2 = (const float*)d_in[12];
    const float* gw1 = (const float*)d_in[13];
    const float* gb1 = (const float*)d_in[14];
    const float* gw2 = (const float*)d_in[15];
    const float* gb2 = (const float*)d_in[16];
    const float* fc1w = (const float*)d_in[17];
    const float* fc1b = (const float*)d_in[18];
    const float* bng  = (const float*)d_in[19];
    const float* bnb  = (const float*)d_in[20];
    const float* fc2w = (const float*)d_in[21];
    const float* fc2b = (const float*)d_in[22];

    int N = in_sizes[0] / 3;
    int E = in_sizes[2] / 3;
    int B = in_sizes[3];
    float* out = (float*)d_out;

    int nsb = (N + SCAN_B - 1) / SCAN_B;   // scan blocks (196 for N=100K)
    const size_t WPK = 2048;               // packed weights (h2), padded

    size_t need = sizeof(h2) * WPK
                + sizeof(unsigned int) * (size_t)E * 8                 /* hbuf16 */
                + sizeof(int) * ((size_t)N + (size_t)E + (size_t)N + 1024);

    if (ws_size >= need && nsb <= 1024) {
        // ---- fast path: CSR build + packed-f16 dot2 MLP + fused tail ----
        char* p = (char*)d_ws;
        h2* ew1pk = (h2*)p;                 // 250
        h2* nw1pk = ew1pk + 250;            // 450
        h2* ew2pk = nw1pk + 450;            // 375
        h2* nw2pk = ew2pk + 375;            // 375
        p += sizeof(h2) * WPK;
        unsigned int* hbuf16 = (unsigned int*)p;  p += sizeof(unsigned int) * (size_t)E * 8;
        int* deg  = (int*)p;            p += sizeof(int) * (size_t)N;
        int* rank = (int*)p;            p += sizeof(int) * (size_t)E;
        int* base = (int*)p;            p += sizeof(int) * (size_t)N;
        int* bsum = (int*)p;            p += sizeof(int) * 1024;

        hipMemsetAsync(deg, 0, sizeof(int) * (size_t)N, stream);

        int eb = (E + 255) / 256;
        deg_rank_prep_kernel<<<eb, 256, 0, stream>>>(
            ei, deg, rank, E, ew1, nw1, ew2, nw2, ew1pk, nw1pk, ew2pk, nw2pk);

        scan1_kernel<<<nsb, SCAN_B, 0, stream>>>(deg, base, bsum, N);
        scan23_kernel<<<nsb, SCAN_B, 0, stream>>>(base, bsum, N);

        edge_mlp_fused_kernel<<<eb, 256, 0, stream>>>(
            x, ei, ea, ew1pk, eb1, ew2pk, eb2, nw1pk, nb1, nw2pk, nb2,
            base, rank, hbuf16, E);

        tail_kernel<<<B, 256, 0, stream>>>(
            hbuf16, deg, base, batch, N,
            u, gw1, gb1, gw2, gb2, fc1w, fc1b, bng, bnb, fc2w, fc2b, out);
    } else {
        // ---- fallback: round-1 atomic path (fp32 exact) ----
        float* x2sum = (float*)d_ws;
        float* cnt   = x2sum + (size_t)N * D3;
        float* bx    = cnt + N;
        float* brelu = bx + (size_t)B * D3;
        float* ncnt  = brelu + (size_t)B * D3;

        hipMemsetAsync(x2sum, 0, sizeof(float) * ((size_t)N * D3 + N), stream);

        int eb = (E + 255) / 256;
        edge_node_atomic_kernel<<<eb, 256, 0, stream>>>(
            x, ei, ea, ew1, eb1, ew2, eb2, nw1, nb1, nw2, nb2, x2sum, cnt, E);

        graph_sum_atomic_kernel<<<B, 256, 0, stream>>>(x2sum, cnt, batch, N, bx, brelu, ncnt);

        int fb = (B + 255) / 256;
        final_kernel<<<fb, 256, 0, stream>>>(
            u, gw1, gb1, gw2, gb2, fc1w, fc1b, bng, bnb, fc2w, fc2b,
            bx, brelu, ncnt, out, B);
    }
}